// Round 3
// baseline (199.708 us; speedup 1.0000x reference)
//
#include <hip/hip_runtime.h>

namespace {

constexpr int kB  = 16;    // batches
constexpr int kP  = 8;     // pieces
constexpr int kNT = 512;   // time steps (incl. t=0)
constexpr int kNX = 2048;  // cells
constexpr int kT  = 512;   // threads per block
constexpr int kC  = kNX / kT;  // 4 cells per thread

// Raw workgroup barrier WITHOUT the vmcnt(0) drain that __syncthreads emits.
// Only LDS ops need ordering across it (global stores are private per thread).
// asm memory clobbers on both sides = IR-level fence; sched_barrier(0) stops
// the machine scheduler hoisting the post-barrier ds_reads (guide rule #18).
__device__ __forceinline__ void block_barrier() {
    asm volatile("s_waitcnt lgkmcnt(0)" ::: "memory");
    __builtin_amdgcn_s_barrier();
    __builtin_amdgcn_sched_barrier(0);
    asm volatile("" ::: "memory");
}

// Godunov flux for concave f(u)=u(1-u), argmax at 0.5:
//   uL<=uR: min(fL,fR)            (concave -> min at an endpoint)
//   uL> uR: f(med3(0.5,uR,uL))    (max over [uR,uL]; == 0.25 iff 0.5 inside)
__device__ __forceinline__ float gflux(float uL, float uR, float fL, float fR) {
    float fmn = fminf(fL, fR);
    float m   = fmaxf(uR, fminf(0.5f, uL));     // med3 when uL>uR
    float fmx = __builtin_fmaf(-m, m, m);       // f(m) = m - m^2
    return (uL <= uR) ? fmn : fmx;
}

__global__ __launch_bounds__(kT)
void godunov_kernel(const float* __restrict__ xs,   // (B, P+1)
                    const float* __restrict__ ks,   // (B, P)
                    const int*   __restrict__ pm,   // (B, P)
                    const float* __restrict__ dxp,  // (B,)
                    const float* __restrict__ dtp,  // (B,)
                    float* __restrict__ out)        // (B, 1, NT, NX) fp32
{
    // w=2 temporal blocking: exchange 2-wide halos, advance 2 steps per barrier.
    __shared__ float2 sHi[2][kT];  // thread t publishes {u[2],u[3]}
    __shared__ float2 sLo[2][kT];  // thread t publishes {u[0],u[1]}

    const int b = blockIdx.x;
    const int t = threadIdx.x;
    const float dxv = dxp[0];
    const float lam = dtp[0] / dxv;

    // ---- initial condition ----
    int npieces = 0;
    float bnds[kP];
#pragma unroll
    for (int j = 0; j < kP; ++j) {
        int m = pm[b * kP + j];
        npieces += m;
        bnds[j] = m ? xs[b * (kP + 1) + j + 1] : __builtin_inff();
    }
    const int cap = npieces - 1;

    float u[kC];
#pragma unroll
    for (int c = 0; c < kC; ++c) {
        int i = t * kC + c;
        float xc = ((float)i + 0.5f) * dxv;
        int idx = 0;
#pragma unroll
        for (int j = 0; j < kP; ++j) idx += (xc >= bnds[j]) ? 1 : 0;
        idx = min(idx, cap);
        u[c] = ks[b * kP + idx];
    }

    const float gLr = u[0];       // ghost value; meaningful only in t==0
    const float gRr = u[kC - 1];  // ghost value; meaningful only in t==kT-1

    sHi[0][t] = make_float2(u[2], u[3]);
    sLo[0][t] = make_float2(u[0], u[1]);

    float4* orow = reinterpret_cast<float4*>(out + ((size_t)b * kNT) * kNX + (size_t)t * kC);
    const int rowStride = kNX / kC;  // in float4 units

    *orow = make_float4(u[0], u[1], u[2], u[3]);  // row 0 = IC
    orow += rowStride;

    block_barrier();

    int cur = 0;
#pragma unroll 1
    for (int g = 0; g < (kNT - 1) / 2; ++g) {   // 255 groups -> rows 1..510
        float2 hiL, loR;
        if (t > 0)      hiL = sHi[cur][t - 1]; else hiL = make_float2(gLr, gLr);
        if (t < kT - 1) loR = sLo[cur][t + 1]; else loR = make_float2(gRr, gRr);

        // e[j] = u^s at cell (i0 - 2 + j), j = 0..7
        float e[8] = { hiL.x, hiL.y, u[0], u[1], u[2], u[3], loR.x, loR.y };
        float fe[8];
#pragma unroll
        for (int j = 0; j < 8; ++j) fe[j] = __builtin_fmaf(-e[j], e[j], e[j]);
        float Fe[7];
#pragma unroll
        for (int j = 0; j < 7; ++j) Fe[j] = gflux(e[j], e[j + 1], fe[j], fe[j + 1]);

        // step s+1 on cells (i0-1 .. i0+4): v[k] = new e[k+1]
        float v[6];
#pragma unroll
        for (int k = 0; k < 6; ++k) v[k] = __builtin_fmaf(-lam, Fe[k + 1] - Fe[k], e[k + 1]);
        if (t == 0)      v[0] = gLr;  // ghost position stays gL
        if (t == kT - 1) v[5] = gRr;  // ghost position stays gR

        *orow = make_float4(v[1], v[2], v[3], v[4]);  // row s+1
        orow += rowStride;

        // step s+2 on own cells: u'[c] from v[c..c+2]
        float fv[6];
#pragma unroll
        for (int k = 0; k < 6; ++k) fv[k] = __builtin_fmaf(-v[k], v[k], v[k]);
        float Fv[5];
#pragma unroll
        for (int k = 0; k < 5; ++k) Fv[k] = gflux(v[k], v[k + 1], fv[k], fv[k + 1]);
#pragma unroll
        for (int c = 0; c < kC; ++c) u[c] = __builtin_fmaf(-lam, Fv[c + 1] - Fv[c], v[c + 1]);

        *orow = make_float4(u[0], u[1], u[2], u[3]);  // row s+2
        orow += rowStride;

        int nxt = cur ^ 1;
        sHi[nxt][t] = make_float2(u[2], u[3]);
        sLo[nxt][t] = make_float2(u[0], u[1]);
        block_barrier();
        cur = nxt;
    }

    // tail: one single step for row kNT-1 (kNT-1 = 511 is odd)
    {
        float um = (t > 0)      ? sHi[cur][t - 1].y : gLr;
        float up = (t < kT - 1) ? sLo[cur][t + 1].x : gRr;

        float f[kC];
#pragma unroll
        for (int c = 0; c < kC; ++c) f[c] = __builtin_fmaf(-u[c], u[c], u[c]);
        float fm = __builtin_fmaf(-um, um, um);
        float fp = __builtin_fmaf(-up, up, up);

        float F[kC + 1];
        F[0] = gflux(um, u[0], fm, f[0]);
#pragma unroll
        for (int c = 1; c < kC; ++c) F[c] = gflux(u[c - 1], u[c], f[c - 1], f[c]);
        F[kC] = gflux(u[kC - 1], up, f[kC - 1], fp);

#pragma unroll
        for (int c = 0; c < kC; ++c) u[c] = __builtin_fmaf(-lam, F[c + 1] - F[c], u[c]);

        *orow = make_float4(u[0], u[1], u[2], u[3]);
    }
}

}  // namespace

extern "C" void kernel_launch(void* const* d_in, const int* in_sizes, int n_in,
                              void* d_out, int out_size, void* d_ws, size_t ws_size,
                              hipStream_t stream) {
    const float* xs  = (const float*)d_in[0];
    const float* ks  = (const float*)d_in[1];
    const int*   pm  = (const int*)d_in[2];
    const float* dxv = (const float*)d_in[3];
    const float* dtv = (const float*)d_in[4];
    // d_in[5] = t_coords: only carries the (NT, NX) shape; values unused.
    float* out = (float*)d_out;

    hipLaunchKernelGGL(godunov_kernel, dim3(kB), dim3(kT), 0, stream,
                       xs, ks, pm, dxv, dtv, out);
}

// Round 4
// 117.574 us; speedup vs baseline: 1.6986x; 1.6986x over previous
//
#include <hip/hip_runtime.h>

namespace {

constexpr int kB  = 16;    // batches
constexpr int kP  = 8;     // pieces
constexpr int kNT = 512;   // time steps (incl. t=0)
constexpr int kNX = 2048;  // cells
constexpr int kW  = 64;    // time steps advanced per launch
constexpr int kChunk = 128;                 // cells owned per wave
constexpr int kChunksPerB = kNX / kChunk;   // 16
// region per wave = kChunk + 2*kW = 256 cells = 64 lanes x 4 cells

// Godunov flux for concave f(u)=u(1-u), argmax 0.5:
//   uL<=uR: min(fL,fR); uL>uR: f(med3(0.5,uR,uL))  (== 0.25 iff 0.5 in [uR,uL])
__device__ __forceinline__ float gflux(float uL, float uR, float fL, float fR) {
    float fmn = fminf(fL, fR);
    float m   = fmaxf(uR, fminf(0.5f, uL));
    float fmx = __builtin_fmaf(-m, m, m);   // f(m) = m - m^2
    return (uL <= uR) ? fmn : fmx;
}

__global__ __launch_bounds__(64)
void godunov_step(const float* __restrict__ xs,   // (B, P+1)
                  const float* __restrict__ ks,   // (B, P)
                  const int*   __restrict__ pm,   // (B, P)
                  const float* __restrict__ dxp,  // (B,)
                  const float* __restrict__ dtp,  // (B,)
                  float* __restrict__ out,        // (B,1,NT,NX) fp32
                  int t0, int nsteps)             // advance rows t0+1 .. t0+nsteps
{
    const int bx   = blockIdx.x;
    const int b    = bx >> 4;        // batch
    const int k    = bx & 15;        // chunk within batch
    const int lane = threadIdx.x;    // 0..63, one wave per block
    const int rs   = k * kChunk - kW;    // region start (cell index, may be <0)
    const int gi0  = rs + 4 * lane;      // this lane's first cell

    const float dxv = dxp[0];
    const float lam = dtp[0] / dxv;

    // ---- piecewise-constant IC parameters ----
    int np = 0;
    float bnds[kP];
#pragma unroll
    for (int j = 0; j < kP; ++j) {
        int m = pm[b * kP + j];
        np += m;
        bnds[j] = m ? xs[b * (kP + 1) + j + 1] : __builtin_inff();
    }
    const int cap = np - 1;

    auto icval = [&](int gi) -> float {
        float xc = ((float)gi + 0.5f) * dxv;
        int idx = 0;
#pragma unroll
        for (int j = 0; j < kP; ++j) idx += (xc >= bnds[j]) ? 1 : 0;
        idx = min(idx, cap);
        return ks[b * kP + idx];
    };

    // Constant ghost values (reference: gL/gR frozen from the IC endpoints).
    const float gL = icval(0);
    const float gR = icval(kNX - 1);

    // Per-cell domain mask + ghost value (cells outside [0,NX) are pinned).
    bool  inD[4];
    float gv[4];
#pragma unroll
    for (int c = 0; c < 4; ++c) {
        int gi = gi0 + c;
        inD[c] = (gi >= 0) && (gi < kNX);
        gv[c]  = (gi < 0) ? gL : gR;
    }

    // ---- seed region state at row t0 ----
    float u[4];
    if (t0 == 0) {
#pragma unroll
        for (int c = 0; c < 4; ++c)
            u[c] = inD[c] ? icval(gi0 + c) : gv[c];
    } else {
        const float* rin = out + ((size_t)b * kNT + t0) * kNX;
        if (gi0 >= 0 && gi0 + 3 < kNX) {          // float4-aligned, all-in or all-out
            float4 v = *reinterpret_cast<const float4*>(rin + gi0);
            u[0] = v.x; u[1] = v.y; u[2] = v.z; u[3] = v.w;
        } else {
            float g = (gi0 < 0) ? gL : gR;
            u[0] = g; u[1] = g; u[2] = g; u[3] = g;
        }
    }

    // Lanes 16..47 hold exactly the owned chunk (cells k*128 .. k*128+127).
    const bool writer = (lane >= 16) && (lane < 48);
    float* prow = out + ((size_t)b * kNT + t0) * kNX;   // row t0

    if (t0 == 0 && writer) {
        *reinterpret_cast<float4*>(prow + gi0) = make_float4(u[0], u[1], u[2], u[3]);
    }

#pragma unroll 1
    for (int j = 1; j <= nsteps; ++j) {
        // halo exchange: neighbor cells via intra-wave shuffle (no LDS/barrier)
        float um = __shfl_up(u[3], 1, 64);    // cell gi0-1 (garbage in lane 0: edge-invalid ok)
        float up = __shfl_down(u[0], 1, 64);  // cell gi0+4 (garbage in lane 63)

        float fm = __builtin_fmaf(-um, um, um);
        float fp = __builtin_fmaf(-up, up, up);
        float fu[4];
#pragma unroll
        for (int c = 0; c < 4; ++c) fu[c] = __builtin_fmaf(-u[c], u[c], u[c]);

        float F[5];
        F[0] = gflux(um,   u[0], fm,    fu[0]);
        F[1] = gflux(u[0], u[1], fu[0], fu[1]);
        F[2] = gflux(u[1], u[2], fu[1], fu[2]);
        F[3] = gflux(u[2], u[3], fu[2], fu[3]);
        F[4] = gflux(u[3], up,   fu[3], fp);

#pragma unroll
        for (int c = 0; c < 4; ++c) {
            float un = __builtin_fmaf(-lam, F[c + 1] - F[c], u[c]);
            u[c] = inD[c] ? un : gv[c];   // pin out-of-domain cells to ghosts
        }

        prow += kNX;
        if (writer)
            *reinterpret_cast<float4*>(prow + gi0) = make_float4(u[0], u[1], u[2], u[3]);
    }
}

}  // namespace

extern "C" void kernel_launch(void* const* d_in, const int* in_sizes, int n_in,
                              void* d_out, int out_size, void* d_ws, size_t ws_size,
                              hipStream_t stream) {
    const float* xs  = (const float*)d_in[0];
    const float* ks  = (const float*)d_in[1];
    const int*   pm  = (const int*)d_in[2];
    const float* dxv = (const float*)d_in[3];
    const float* dtv = (const float*)d_in[4];
    // d_in[5] = t_coords: only carries the (NT, NX) shape; values unused.
    float* out = (float*)d_out;

    // Ghost-zone temporal blocking: each launch advances kW rows; halos (width
    // kW) are re-seeded from the previous launch's output rows (stream-ordered).
    for (int t0 = 0; t0 < kNT - 1; t0 += kW) {
        int ns = min(kW, (kNT - 1) - t0);
        hipLaunchKernelGGL(godunov_step, dim3(kB * kChunksPerB), dim3(64), 0, stream,
                           xs, ks, pm, dxv, dtv, out, t0, ns);
    }
}

// Round 5
// 94.723 us; speedup vs baseline: 2.1083x; 1.2412x over previous
//
#include <hip/hip_runtime.h>

namespace {

constexpr int kB  = 16;    // batches
constexpr int kP  = 8;     // pieces
constexpr int kNT = 512;   // time steps (incl. t=0)
constexpr int kNX = 2048;  // cells
constexpr int kW  = 64;    // time steps advanced per launch
constexpr int kChunk = 128;                 // cells owned per wave
constexpr int kChunksPerB = kNX / kChunk;   // 16
// region per wave = kChunk + 2*kW = 256 cells = 64 lanes x 4 cells

// Cross-lane shift by one lane via DPP (VALU, ~2 cyc; no LDS round-trip).
// wave_shr:1 (0x138): lane i <- lane i-1 ; wave_shl:1 (0x130): lane i <- lane i+1.
// bound_ctrl=1 -> edge lane reads 0 (harmless: region-edge lanes are
// garbage-by-design; domain edges are pinned by inD below).
__device__ __forceinline__ float dpp_shr1(float x) {
    return __builtin_bit_cast(float,
        __builtin_amdgcn_update_dpp(0, __builtin_bit_cast(int, x), 0x138, 0xF, 0xF, true));
}
__device__ __forceinline__ float dpp_shl1(float x) {
    return __builtin_bit_cast(float,
        __builtin_amdgcn_update_dpp(0, __builtin_bit_cast(int, x), 0x130, 0xF, 0xF, true));
}

__device__ __forceinline__ float fpar(float u) {  // f(u) = u - u^2 (single-rounded)
    return __builtin_fmaf(-u, u, u);
}

__global__ __launch_bounds__(64)
void godunov_step(const float* __restrict__ xs,   // (B, P+1)
                  const float* __restrict__ ks,   // (B, P)
                  const int*   __restrict__ pm,   // (B, P)
                  const float* __restrict__ dxp,  // (B,)
                  const float* __restrict__ dtp,  // (B,)
                  float* __restrict__ out,        // (B,1,NT,NX) fp32
                  int t0, int nsteps)             // advance rows t0+1 .. t0+nsteps
{
    const int bx   = blockIdx.x;
    const int b    = bx >> 4;        // batch
    const int k    = bx & 15;        // chunk within batch
    const int lane = threadIdx.x;    // 0..63, one wave per block
    const int rs   = k * kChunk - kW;    // region start (cell index, may be <0)
    const int gi0  = rs + 4 * lane;      // this lane's first cell

    const float dxv = dxp[0];
    const float lam = dtp[0] / dxv;

    // ---- piecewise-constant IC parameters ----
    int np = 0;
    float bnds[kP];
#pragma unroll
    for (int j = 0; j < kP; ++j) {
        int m = pm[b * kP + j];
        np += m;
        bnds[j] = m ? xs[b * (kP + 1) + j + 1] : __builtin_inff();
    }
    const int cap = np - 1;

    auto icval = [&](int gi) -> float {
        float xc = ((float)gi + 0.5f) * dxv;
        int idx = 0;
#pragma unroll
        for (int j = 0; j < kP; ++j) idx += (xc >= bnds[j]) ? 1 : 0;
        idx = min(idx, cap);
        return ks[b * kP + idx];
    };

    // Constant ghost values (reference: gL/gR frozen from the IC endpoints).
    const float gL = icval(0);
    const float gR = icval(kNX - 1);

    // Per-cell domain mask + ghost value (cells outside [0,NX) are pinned).
    bool  inD[4];
    float gv[4];
#pragma unroll
    for (int c = 0; c < 4; ++c) {
        int gi = gi0 + c;
        inD[c] = (gi >= 0) && (gi < kNX);
        gv[c]  = (gi < 0) ? gL : gR;
    }

    // ---- seed region state at row t0 ----
    float u[4];
    if (t0 == 0) {
#pragma unroll
        for (int c = 0; c < 4; ++c)
            u[c] = inD[c] ? icval(gi0 + c) : gv[c];
    } else {
        const float* rin = out + ((size_t)b * kNT + t0) * kNX;
        if (gi0 >= 0 && gi0 + 3 < kNX) {          // float4-aligned, all-in or all-out
            float4 v = *reinterpret_cast<const float4*>(rin + gi0);
            u[0] = v.x; u[1] = v.y; u[2] = v.z; u[3] = v.w;
        } else {
            float g = (gi0 < 0) ? gL : gR;
            u[0] = g; u[1] = g; u[2] = g; u[3] = g;
        }
    }

    // Lanes 16..47 hold exactly the owned chunk (cells k*128 .. k*128+127).
    const bool writer = (lane >= 16) && (lane < 48);
    float* prow = out + ((size_t)b * kNT + t0) * kNX;   // row t0

    if (t0 == 0 && writer) {
        *reinterpret_cast<float4*>(prow + gi0) = make_float4(u[0], u[1], u[2], u[3]);
    }

#pragma unroll 1
    for (int j = 1; j <= nsteps; ++j) {
        // halo exchange via DPP (no LDS, no barrier, no lgkmcnt)
        float um = dpp_shr1(u[3]);    // cell gi0-1
        float up = dpp_shl1(u[0]);    // cell gi0+4

        // Godunov flux, branchless concave form:
        //   F(uL,uR) = min( f(min(uL,1/2)), f(max(uR,1/2)) )
        // fl[c] = f(min(u,1/2)) (cell as uL side), fh[c] = f(max(u,1/2)) (uR side)
        float fl[4], fh[4];
#pragma unroll
        for (int c = 0; c < 4; ++c) {
            fl[c] = fpar(fminf(u[c], 0.5f));
            fh[c] = fpar(fmaxf(u[c], 0.5f));
        }
        float flm = fpar(fminf(um, 0.5f));
        float fhp = fpar(fmaxf(up, 0.5f));

        float F[5];
        F[0] = fminf(flm,   fh[0]);
        F[1] = fminf(fl[0], fh[1]);
        F[2] = fminf(fl[1], fh[2]);
        F[3] = fminf(fl[2], fh[3]);
        F[4] = fminf(fl[3], fhp);

#pragma unroll
        for (int c = 0; c < 4; ++c) {
            float un = __builtin_fmaf(-lam, F[c + 1] - F[c], u[c]);
            u[c] = inD[c] ? un : gv[c];   // pin out-of-domain cells to ghosts
        }

        prow += kNX;
        if (writer)
            *reinterpret_cast<float4*>(prow + gi0) = make_float4(u[0], u[1], u[2], u[3]);
    }
}

}  // namespace

extern "C" void kernel_launch(void* const* d_in, const int* in_sizes, int n_in,
                              void* d_out, int out_size, void* d_ws, size_t ws_size,
                              hipStream_t stream) {
    const float* xs  = (const float*)d_in[0];
    const float* ks  = (const float*)d_in[1];
    const int*   pm  = (const int*)d_in[2];
    const float* dxv = (const float*)d_in[3];
    const float* dtv = (const float*)d_in[4];
    // d_in[5] = t_coords: only carries the (NT, NX) shape; values unused.
    float* out = (float*)d_out;

    // Ghost-zone temporal blocking: each launch advances kW rows; halos (width
    // kW) are re-seeded from the previous launch's output rows (stream-ordered).
    for (int t0 = 0; t0 < kNT - 1; t0 += kW) {
        int ns = min(kW, (kNT - 1) - t0);
        hipLaunchKernelGGL(godunov_step, dim3(kB * kChunksPerB), dim3(64), 0, stream,
                           xs, ks, pm, dxv, dtv, out, t0, ns);
    }
}